// Round 3
// baseline (150.684 us; speedup 1.0000x reference)
//
#include <hip/hip_runtime.h>
#include <hip/hip_bf16.h>
#include <cstddef>
#include <cstdint>

#define B_ 8
#define H_ 8
#define N_ 512
#define K_ 16
#define NN_ (N_*N_)

static constexpr float ALPHA_C = 0.001f;

typedef float f32x4 __attribute__((ext_vector_type(4)));

// -------------------------------------------------------------------------
// Kernel 1: per (b,n): A = sum_g phi[g]*G_g (skew), Om = expm(A) via
// scaling-and-squaring + Taylor-8 Horner, v = Om^T mu, q = 0.5*||v||^2.
// One 256-thread block per matrix; thread (r,c) owns element [r][c].
// Frobenius reduction is wave-level (1 barrier instead of 8).
// -------------------------------------------------------------------------
__global__ __launch_bounds__(256) void expm_kernel(
    const float* __restrict__ mu, const float* __restrict__ phi,
    const float* __restrict__ gen, float* __restrict__ Om,
    float* __restrict__ v, float* __restrict__ q)
{
    const int bn  = blockIdx.x;          // 0..B_*N_-1
    const int tid = threadIdx.x;         // 0..255
    const int r = tid >> 4, c = tid & 15;
    const int rc = (r << 4) | c;
    const int r17 = r * 17;

    __shared__ float Xs[16*17];
    __shared__ float Ps[16*17];
    __shared__ float part[4];
    __shared__ float mus[16];
    __shared__ float vs[16];

    const float p0 = phi[bn*3+0], p1 = phi[bn*3+1], p2 = phi[bn*3+2];
    const float A = p0*gen[rc] + p1*gen[256+rc] + p2*gen[512+rc];

    // Frobenius norm via wave shuffle + 4 partials (1 barrier)
    float t = A * A;
    #pragma unroll
    for (int off = 32; off > 0; off >>= 1) t += __shfl_xor(t, off, 64);
    if ((tid & 63) == 0) part[tid >> 6] = t;
    if (tid < 16) mus[tid] = mu[bn*16 + tid];
    __syncthreads();

    float theta = sqrtf(part[0] + part[1] + part[2] + part[3]);
    int s = 0;
    while (theta > 0.5f && s < 30) { theta *= 0.5f; s++; }
    const float X = A * exp2f((float)(-s));

    // Horner for Taylor-8: P = I + X(I + X/2(I + ... (I + X/8)...))
    Xs[r17 + c] = X;
    Ps[r17 + c] = ((r == c) ? 1.0f : 0.0f) + X * 0.125f;
    __syncthreads();

    for (int d = 7; d >= 1; --d) {
        float acc = 0.f;
        #pragma unroll
        for (int k = 0; k < 16; ++k) acc = fmaf(Xs[r17 + k], Ps[k*17 + c], acc);
        __syncthreads();
        Ps[r17 + c] = ((r == c) ? 1.0f : 0.0f) + acc * (1.0f / (float)d);
        __syncthreads();
    }
    // square s times
    for (int it = 0; it < s; ++it) {
        float acc = 0.f;
        #pragma unroll
        for (int k = 0; k < 16; ++k) acc = fmaf(Ps[r17 + k], Ps[k*17 + c], acc);
        __syncthreads();
        Ps[r17 + c] = acc;
        __syncthreads();
    }

    // store Om (row-major, coalesced)
    Om[(size_t)bn * 256 + rc] = Ps[r17 + c];

    // v[k] = sum_m Om[m][k] * mu[m]   (Om^T mu)
    if (tid < 16) {
        float acc = 0.f;
        #pragma unroll
        for (int m = 0; m < 16; ++m) acc = fmaf(Ps[m*17 + tid], mus[m], acc);
        vs[tid] = acc;
        v[bn*16 + tid] = acc;
    }
    __syncthreads();
    if (tid == 0) {
        float acc = 0.f;
        #pragma unroll
        for (int k = 0; k < 16; ++k) acc = fmaf(vs[k], vs[k], acc);
        q[bn] = 0.5f * acc;
    }
}

// -------------------------------------------------------------------------
// Kernel 2: memory-bound pass over beta. One wave per (b,i); 4 i per block
// sharing a transposed LDS copy of v[b] laid out as float4 chunks over j
// (row stride 129 float4 -> conflict-free ds_read_b128). Per lane: a
// float4 j-chunk, j0 = 4*lane + 256*p, p=0..1. beta h-mean via f32x4
// nontemporal loads (the HBM stream). Butterfly-reduce, rotate by Om_i.
// -------------------------------------------------------------------------
__global__ __launch_bounds__(256, 4) void grad_kernel(
    const float* __restrict__ mu, const float* __restrict__ beta,
    const float* __restrict__ mu_prior, const float* __restrict__ lrp,
    const float* __restrict__ Om, const float* __restrict__ v,
    const float* __restrict__ q, float* __restrict__ out)
{
    __shared__ float v_t[16 * 516];      // 16 rows x 129 float4 (pad 1 f4)
    __shared__ f32x4 q4[128];

    const int blk = blockIdx.x;          // 0..1023
    const int b   = blk >> 7;
    const int i0  = (blk & 127) << 2;
    const int tid = threadIdx.x;
    const int wid = tid >> 6, lane = tid & 63;

    // stage v[b] transposed into LDS (coalesced global read, 2-way LDS
    // write aliasing only -> free)
    const float* vb = v + (size_t)b * N_ * K_;
    for (int f = tid; f < N_ * K_; f += 256) {
        const int j = f >> 4, k = f & 15;
        v_t[k * 516 + j] = vb[f];
    }
    const f32x4* qb4 = (const f32x4*)(q + (size_t)b * N_);
    if (tid < 128) q4[tid] = qb4[tid];
    __syncthreads();

    const int i = i0 + wid;

    float vi[16];
    #pragma unroll
    for (int k = 0; k < 16; ++k) vi[k] = v_t[k * 516 + i];   // broadcast
    const float qi = ((const float*)q4)[i];

    float w1[16], w2[16];
    #pragma unroll
    for (int k = 0; k < 16; ++k) { w1[k] = 0.f; w2[k] = 0.f; }
    float sacc = 0.f, R = 0.f;

    const size_t betaBase = (((size_t)b * H_) * N_ + i) * N_;

    #pragma unroll 1
    for (int p = 0; p < 2; ++p) {
        const int j0 = (lane << 2) | (p << 8);

        // h-mean of beta over this float4 j-chunk (8 x 16B nontemporal)
        const float* bp = beta + betaBase + j0;
        float rx = 0.f, ry = 0.f, rz = 0.f, rw = 0.f;
        #pragma unroll
        for (int h = 0; h < H_; ++h) {
            const f32x4 bt = __builtin_nontemporal_load(
                (const f32x4*)(bp + (size_t)h * NN_));
            rx += bt.x; ry += bt.y; rz += bt.z; rw += bt.w;
        }
        rx *= 0.125f; ry *= 0.125f; rz *= 0.125f; rw *= 0.125f;

        // pass 1: dots vi . vj_u  (16 ds_read_b128)
        float d0 = 0.f, d1 = 0.f, d2 = 0.f, d3 = 0.f;
        #pragma unroll
        for (int k = 0; k < 16; ++k) {
            const f32x4 vj = *(const f32x4*)&v_t[k * 516 + j0];
            d0 = fmaf(vi[k], vj.x, d0);
            d1 = fmaf(vi[k], vj.y, d1);
            d2 = fmaf(vi[k], vj.z, d2);
            d3 = fmaf(vi[k], vj.w, d3);
        }
        const f32x4 qj = q4[lane | (p << 6)];
        const float rkl0 = rx * (qi + qj.x - d0);
        const float rkl1 = ry * (qi + qj.y - d1);
        const float rkl2 = rz * (qi + qj.z - d2);
        const float rkl3 = rw * (qi + qj.w - d3);
        sacc += (rkl0 + rkl1) + (rkl2 + rkl3);
        R    += (rx + ry) + (rz + rw);

        // pass 2: accumulate w1, w2 (re-read b128; stays in LDS pipe)
        #pragma unroll
        for (int k = 0; k < 16; ++k) {
            const f32x4 vj = *(const f32x4*)&v_t[k * 516 + j0];
            float a1 = fmaf(rx, vj.x, w1[k]);
            a1 = fmaf(ry, vj.y, a1);
            a1 = fmaf(rz, vj.z, a1);
            w1[k] = fmaf(rw, vj.w, a1);
            float a2 = fmaf(rkl0, vj.x, w2[k]);
            a2 = fmaf(rkl1, vj.y, a2);
            a2 = fmaf(rkl2, vj.z, a2);
            w2[k] = fmaf(rkl3, vj.w, a2);
        }
    }

    // wave-wide butterfly: every lane ends with the full sums
    #pragma unroll
    for (int off = 32; off > 0; off >>= 1) {
        #pragma unroll
        for (int k = 0; k < 16; ++k) {
            w1[k] += __shfl_xor(w1[k], off, 64);
            w2[k] += __shfl_xor(w2[k], off, 64);
        }
        sacc += __shfl_xor(sacc, off, 64);
        R    += __shfl_xor(R,    off, 64);
    }

    // gvec = (1-s)(R*vi - w1) + s*vi - w2  (rotated frame)
    float gvec[16];
    #pragma unroll
    for (int k = 0; k < 16; ++k)
        gvec[k] = (1.0f - sacc) * (R * vi[k] - w1[k]) + sacc * vi[k] - w2[k];

    if (lane < 16) {
        const float lr = lrp[0];
        const size_t rowi = (size_t)b * N_ + i;
        const float* omr = Om + rowi * 256 + (size_t)lane * 16;
        float S = 0.f;
        #pragma unroll
        for (int c2 = 0; c2 < 16; ++c2) S = fmaf(omr[c2], gvec[c2], S);
        const size_t oi = rowi * 16 + lane;
        const float m0 = mu[oi], mp = mu_prior[oi];
        out[oi] = m0 - lr * (ALPHA_C * (m0 - mp) + S);
    }
}

// -------------------------------------------------------------------------
extern "C" void kernel_launch(void* const* d_in, const int* in_sizes, int n_in,
                              void* d_out, int out_size, void* d_ws, size_t ws_size,
                              hipStream_t stream)
{
    const float* mu   = (const float*)d_in[0];
    const float* beta = (const float*)d_in[1];
    const float* mup  = (const float*)d_in[2];
    const float* phi  = (const float*)d_in[3];
    const float* gen  = (const float*)d_in[4];
    const float* lr   = (const float*)d_in[5];
    float* out = (float*)d_out;

    float* Om = (float*)d_ws;                       // 4096*256 floats = 4 MB
    float* v  = Om + (size_t)4096 * 256;            // 4096*16
    float* q  = v  + (size_t)4096 * 16;             // 4096

    expm_kernel<<<B_ * N_, 256, 0, stream>>>(mu, phi, gen, Om, v, q);
    grad_kernel<<<B_ * (N_ / 4), 256, 0, stream>>>(mu, beta, mup, lr, Om, v, q, out);
}

// Round 4
// 135.645 us; speedup vs baseline: 1.1109x; 1.1109x over previous
//
#include <hip/hip_runtime.h>
#include <hip/hip_bf16.h>
#include <cstddef>
#include <cstdint>

#define B_ 8
#define H_ 8
#define N_ 512
#define K_ 16
#define NN_ (N_*N_)

static constexpr float ALPHA_C = 0.001f;

typedef float f32x4 __attribute__((ext_vector_type(4)));

#define LDSTRIDE 20   // floats per LDS row: 16 + 4 pad, keeps 16B alignment

// -------------------------------------------------------------------------
// Strip matmul helpers. One wave owns one 16x16 matrix:
//   lane -> row r = lane>>2, col strip c0 = 4*(lane&3).
// B operand lives in LDS (row stride LDSTRIDE); per k the b128 read hits
// only 4 distinct addresses (16-way broadcast -> conflict-free & cheap).
// A operand is a register-cached full row (16 floats).
// -------------------------------------------------------------------------
__device__ __forceinline__ void mm_rowB(const float* a, const float* Bbuf,
                                        int c0, f32x4& acc)
{
    #pragma unroll
    for (int k = 0; k < 16; ++k) {
        const f32x4 bk = *(const f32x4*)&Bbuf[k * LDSTRIDE + c0];
        acc.x = fmaf(a[k], bk.x, acc.x);
        acc.y = fmaf(a[k], bk.y, acc.y);
        acc.z = fmaf(a[k], bk.z, acc.z);
        acc.w = fmaf(a[k], bk.w, acc.w);
    }
}

__device__ __forceinline__ void read_row(const float* buf, int r, float* a)
{
    #pragma unroll
    for (int i = 0; i < 4; ++i) {
        const f32x4 t = *(const f32x4*)&buf[r * LDSTRIDE + 4 * i];
        a[4*i]   = t.x; a[4*i+1] = t.y; a[4*i+2] = t.z; a[4*i+3] = t.w;
    }
}

__device__ __forceinline__ void write_strip(float* buf, int r, int c0, f32x4 s)
{
    *(f32x4*)&buf[r * LDSTRIDE + c0] = s;
}

// -------------------------------------------------------------------------
// Kernel 1: per (b,n): A = sum_g phi[g]*G_g (skew), Om = expm(A) via
// scaling-and-squaring + degree-12 Taylor in Paterson-Stockmeyer form
// (5 matmuls + s squarings, theta<=1 -> remainder ~2e-10). One WAVE per
// matrix, no barriers. Emits Om (row-major), v = Om^T mu, q = 0.5*||v||^2.
// -------------------------------------------------------------------------
__global__ __launch_bounds__(256) void expm_kernel(
    const float* __restrict__ mu, const float* __restrict__ phi,
    const float* __restrict__ gen, float* __restrict__ Om,
    float* __restrict__ v, float* __restrict__ q)
{
    __shared__ float lds[4][2][16 * LDSTRIDE];

    const int tid  = threadIdx.x;
    const int w    = tid >> 6, lane = tid & 63;
    const int r    = lane >> 2, c0 = (lane & 3) << 2;
    const int bn   = (blockIdx.x << 2) | w;

    float* U0 = lds[w][0];
    float* U1 = lds[w][1];

    // A strip = sum_g phi_g * G_g
    const float p0 = phi[bn*3+0], p1 = phi[bn*3+1], p2 = phi[bn*3+2];
    const int gidx = r * 16 + c0;
    const f32x4 g0 = *(const f32x4*)&gen[gidx];
    const f32x4 g1 = *(const f32x4*)&gen[256 + gidx];
    const f32x4 g2 = *(const f32x4*)&gen[512 + gidx];
    f32x4 As;
    As.x = p0*g0.x + p1*g1.x + p2*g2.x;
    As.y = p0*g0.y + p1*g1.y + p2*g2.y;
    As.z = p0*g0.z + p1*g1.z + p2*g2.z;
    As.w = p0*g0.w + p1*g1.w + p2*g2.w;

    // Frobenius norm -> scaling exponent (wave-uniform)
    float t = As.x*As.x + As.y*As.y + As.z*As.z + As.w*As.w;
    #pragma unroll
    for (int m = 1; m <= 32; m <<= 1) t += __shfl_xor(t, m, 64);
    float theta = sqrtf(t);
    int s = 0;
    while (theta > 1.0f && s < 30) { theta *= 0.5f; ++s; }
    const float sc = exp2f((float)(-s));
    const f32x4 Xs = As * sc;

    // X into U0; cache X row
    write_strip(U0, r, c0, Xs);
    float xrow[16];
    read_row(U0, r, xrow);

    // A2 = X*X
    f32x4 a2s = {0.f, 0.f, 0.f, 0.f};
    mm_rowB(xrow, U0, c0, a2s);
    write_strip(U1, r, c0, a2s);

    // A3 = X*A2 (strip only; never needed as a matmul operand)
    f32x4 a3s = {0.f, 0.f, 0.f, 0.f};
    mm_rowB(xrow, U1, c0, a3s);

    // A4 = A2*A2
    float a2row[16];
    read_row(U1, r, a2row);
    f32x4 a4s = {0.f, 0.f, 0.f, 0.f};
    mm_rowB(a2row, U1, c0, a4s);
    write_strip(U0, r, c0, a4s);       // U0 (X) dead as matmul operand now
    float a4row[16];
    read_row(U0, r, a4row);

    // Degree-3 coefficient blocks (all register strips):
    // T12 = C0 + A4*(C1 + A4*(C2 + c12*A4))
    f32x4 di = {0.f, 0.f, 0.f, 0.f};
    if (r >= c0 && r < c0 + 4) ((float*)&di)[r - c0] = 1.0f;

    const f32x4 C0 = di + Xs + a2s * 0.5f + a3s * (1.0f/6.0f);
    const f32x4 C1 = di * (1.0f/24.0f) + Xs * (1.0f/120.0f)
                   + a2s * (1.0f/720.0f) + a3s * (1.0f/5040.0f);
    const f32x4 Q2 = di * (1.0f/40320.0f) + Xs * (1.0f/362880.0f)
                   + a2s * (1.0f/3628800.0f) + a3s * (1.0f/39916800.0f)
                   + a4s * (1.0f/479001600.0f);

    // T1 = C1 + A4*Q2
    write_strip(U1, r, c0, Q2);
    f32x4 T1 = C1;
    mm_rowB(a4row, U1, c0, T1);

    // P = C0 + A4*T1
    write_strip(U1, r, c0, T1);
    f32x4 P = C0;
    mm_rowB(a4row, U1, c0, P);

    // s squarings (s is wave-uniform; no barriers -> divergence-safe)
    for (int it = 0; it < s; ++it) {
        write_strip(U1, r, c0, P);
        float prow[16];
        read_row(U1, r, prow);
        f32x4 Pn = {0.f, 0.f, 0.f, 0.f};
        mm_rowB(prow, U1, c0, Pn);
        P = Pn;
    }

    // store Om row-major (element [r][c] at r*16+c), coalesced b128
    *(f32x4*)&Om[(size_t)bn * 256 + r * 16 + c0] = P;

    // v[c] = sum_r Om[r][c] * mu[r]; reduce over r (xor masks 4..32)
    const float mur = mu[bn * 16 + r];
    f32x4 vc = P * mur;
    #pragma unroll
    for (int m = 4; m <= 32; m <<= 1) {
        vc.x += __shfl_xor(vc.x, m, 64);
        vc.y += __shfl_xor(vc.y, m, 64);
        vc.z += __shfl_xor(vc.z, m, 64);
        vc.w += __shfl_xor(vc.w, m, 64);
    }
    if (r == 0) *(f32x4*)&v[bn * 16 + c0] = vc;

    float qp = vc.x*vc.x + vc.y*vc.y + vc.z*vc.z + vc.w*vc.w;
    qp += __shfl_xor(qp, 1, 64);
    qp += __shfl_xor(qp, 2, 64);
    if (lane == 0) q[bn] = 0.5f * qp;
}

// -------------------------------------------------------------------------
// Kernel 2 (unchanged from R3): memory-bound pass over beta. One wave per
// (b,i); 4 i per block sharing a transposed LDS copy of v[b] in float4
// chunks over j (row stride 129 f4 -> conflict-free ds_read_b128). beta
// h-mean via f32x4 nontemporal loads. Butterfly-reduce, rotate by Om_i.
// -------------------------------------------------------------------------
__global__ __launch_bounds__(256, 4) void grad_kernel(
    const float* __restrict__ mu, const float* __restrict__ beta,
    const float* __restrict__ mu_prior, const float* __restrict__ lrp,
    const float* __restrict__ Om, const float* __restrict__ v,
    const float* __restrict__ q, float* __restrict__ out)
{
    __shared__ float v_t[16 * 516];      // 16 rows x 129 float4 (pad 1 f4)
    __shared__ f32x4 q4[128];

    const int blk = blockIdx.x;          // 0..1023
    const int b   = blk >> 7;
    const int i0  = (blk & 127) << 2;
    const int tid = threadIdx.x;
    const int wid = tid >> 6, lane = tid & 63;

    const float* vb = v + (size_t)b * N_ * K_;
    for (int f = tid; f < N_ * K_; f += 256) {
        const int j = f >> 4, k = f & 15;
        v_t[k * 516 + j] = vb[f];
    }
    const f32x4* qb4 = (const f32x4*)(q + (size_t)b * N_);
    if (tid < 128) q4[tid] = qb4[tid];
    __syncthreads();

    const int i = i0 + wid;

    float vi[16];
    #pragma unroll
    for (int k = 0; k < 16; ++k) vi[k] = v_t[k * 516 + i];   // broadcast
    const float qi = ((const float*)q4)[i];

    float w1[16], w2[16];
    #pragma unroll
    for (int k = 0; k < 16; ++k) { w1[k] = 0.f; w2[k] = 0.f; }
    float sacc = 0.f, R = 0.f;

    const size_t betaBase = (((size_t)b * H_) * N_ + i) * N_;

    #pragma unroll 1
    for (int p = 0; p < 2; ++p) {
        const int j0 = (lane << 2) | (p << 8);

        const float* bp = beta + betaBase + j0;
        float rx = 0.f, ry = 0.f, rz = 0.f, rw = 0.f;
        #pragma unroll
        for (int h = 0; h < H_; ++h) {
            const f32x4 bt = __builtin_nontemporal_load(
                (const f32x4*)(bp + (size_t)h * NN_));
            rx += bt.x; ry += bt.y; rz += bt.z; rw += bt.w;
        }
        rx *= 0.125f; ry *= 0.125f; rz *= 0.125f; rw *= 0.125f;

        float d0 = 0.f, d1 = 0.f, d2 = 0.f, d3 = 0.f;
        #pragma unroll
        for (int k = 0; k < 16; ++k) {
            const f32x4 vj = *(const f32x4*)&v_t[k * 516 + j0];
            d0 = fmaf(vi[k], vj.x, d0);
            d1 = fmaf(vi[k], vj.y, d1);
            d2 = fmaf(vi[k], vj.z, d2);
            d3 = fmaf(vi[k], vj.w, d3);
        }
        const f32x4 qj = q4[lane | (p << 6)];
        const float rkl0 = rx * (qi + qj.x - d0);
        const float rkl1 = ry * (qi + qj.y - d1);
        const float rkl2 = rz * (qi + qj.z - d2);
        const float rkl3 = rw * (qi + qj.w - d3);
        sacc += (rkl0 + rkl1) + (rkl2 + rkl3);
        R    += (rx + ry) + (rz + rw);

        #pragma unroll
        for (int k = 0; k < 16; ++k) {
            const f32x4 vj = *(const f32x4*)&v_t[k * 516 + j0];
            float a1 = fmaf(rx, vj.x, w1[k]);
            a1 = fmaf(ry, vj.y, a1);
            a1 = fmaf(rz, vj.z, a1);
            w1[k] = fmaf(rw, vj.w, a1);
            float a2 = fmaf(rkl0, vj.x, w2[k]);
            a2 = fmaf(rkl1, vj.y, a2);
            a2 = fmaf(rkl2, vj.z, a2);
            w2[k] = fmaf(rkl3, vj.w, a2);
        }
    }

    #pragma unroll
    for (int off = 32; off > 0; off >>= 1) {
        #pragma unroll
        for (int k = 0; k < 16; ++k) {
            w1[k] += __shfl_xor(w1[k], off, 64);
            w2[k] += __shfl_xor(w2[k], off, 64);
        }
        sacc += __shfl_xor(sacc, off, 64);
        R    += __shfl_xor(R,    off, 64);
    }

    float gvec[16];
    #pragma unroll
    for (int k = 0; k < 16; ++k)
        gvec[k] = (1.0f - sacc) * (R * vi[k] - w1[k]) + sacc * vi[k] - w2[k];

    if (lane < 16) {
        const float lr = lrp[0];
        const size_t rowi = (size_t)b * N_ + i;
        const float* omr = Om + rowi * 256 + (size_t)lane * 16;
        float S = 0.f;
        #pragma unroll
        for (int c2 = 0; c2 < 16; ++c2) S = fmaf(omr[c2], gvec[c2], S);
        const size_t oi = rowi * 16 + lane;
        const float m0 = mu[oi], mp = mu_prior[oi];
        out[oi] = m0 - lr * (ALPHA_C * (m0 - mp) + S);
    }
}

// -------------------------------------------------------------------------
extern "C" void kernel_launch(void* const* d_in, const int* in_sizes, int n_in,
                              void* d_out, int out_size, void* d_ws, size_t ws_size,
                              hipStream_t stream)
{
    const float* mu   = (const float*)d_in[0];
    const float* beta = (const float*)d_in[1];
    const float* mup  = (const float*)d_in[2];
    const float* phi  = (const float*)d_in[3];
    const float* gen  = (const float*)d_in[4];
    const float* lr   = (const float*)d_in[5];
    float* out = (float*)d_out;

    float* Om = (float*)d_ws;                       // 4096*256 floats = 4 MB
    float* v  = Om + (size_t)4096 * 256;            // 4096*16
    float* q  = v  + (size_t)4096 * 16;             // 4096

    expm_kernel<<<B_ * N_ / 4, 256, 0, stream>>>(mu, phi, gen, Om, v, q);
    grad_kernel<<<B_ * (N_ / 4), 256, 0, stream>>>(mu, beta, mup, lr, Om, v, q, out);
}

// Round 5
// 133.925 us; speedup vs baseline: 1.1251x; 1.0128x over previous
//
#include <hip/hip_runtime.h>
#include <hip/hip_bf16.h>
#include <cstddef>
#include <cstdint>

#define B_ 8
#define H_ 8
#define N_ 512
#define K_ 16
#define NN_ (N_*N_)

static constexpr float ALPHA_C = 0.001f;

typedef float f32x4 __attribute__((ext_vector_type(4)));

#define LDSTRIDE 20   // floats per LDS row: 16 + 4 pad, keeps 16B alignment

// -------------------------------------------------------------------------
// Strip matmul helpers. One wave owns one 16x16 matrix:
//   lane -> row r = lane>>2, col strip c0 = 4*(lane&3).
// B operand lives in LDS (row stride LDSTRIDE); per k the b128 read hits
// only 4 distinct addresses (16-way broadcast -> conflict-free & cheap).
// A operand is a register-cached full row (16 floats).
// -------------------------------------------------------------------------
__device__ __forceinline__ void mm_rowB(const float* a, const float* Bbuf,
                                        int c0, f32x4& acc)
{
    #pragma unroll
    for (int k = 0; k < 16; ++k) {
        const f32x4 bk = *(const f32x4*)&Bbuf[k * LDSTRIDE + c0];
        acc.x = fmaf(a[k], bk.x, acc.x);
        acc.y = fmaf(a[k], bk.y, acc.y);
        acc.z = fmaf(a[k], bk.z, acc.z);
        acc.w = fmaf(a[k], bk.w, acc.w);
    }
}

__device__ __forceinline__ void read_row(const float* buf, int r, float* a)
{
    #pragma unroll
    for (int i = 0; i < 4; ++i) {
        const f32x4 t = *(const f32x4*)&buf[r * LDSTRIDE + 4 * i];
        a[4*i]   = t.x; a[4*i+1] = t.y; a[4*i+2] = t.z; a[4*i+3] = t.w;
    }
}

__device__ __forceinline__ void write_strip(float* buf, int r, int c0, f32x4 s)
{
    *(f32x4*)&buf[r * LDSTRIDE + c0] = s;
}

// -------------------------------------------------------------------------
// Kernel 1: per (b,n): A = sum_g phi[g]*G_g (skew), Om = expm(A) via
// scaling-and-squaring + degree-12 Taylor in Paterson-Stockmeyer form
// (5 matmuls + s squarings; theta<=2 -> remainder ~1.3e-6, s=0 typical).
// One WAVE per matrix, no barriers. Emits Om, v = Om^T mu, q = 0.5||v||^2.
// -------------------------------------------------------------------------
__global__ __launch_bounds__(256) void expm_kernel(
    const float* __restrict__ mu, const float* __restrict__ phi,
    const float* __restrict__ gen, float* __restrict__ Om,
    float* __restrict__ v, float* __restrict__ q)
{
    __shared__ float lds[4][2][16 * LDSTRIDE];

    const int tid  = threadIdx.x;
    const int w    = tid >> 6, lane = tid & 63;
    const int r    = lane >> 2, c0 = (lane & 3) << 2;
    const int bn   = (blockIdx.x << 2) | w;

    float* U0 = lds[w][0];
    float* U1 = lds[w][1];

    // A strip = sum_g phi_g * G_g
    const float p0 = phi[bn*3+0], p1 = phi[bn*3+1], p2 = phi[bn*3+2];
    const int gidx = r * 16 + c0;
    const f32x4 g0 = *(const f32x4*)&gen[gidx];
    const f32x4 g1 = *(const f32x4*)&gen[256 + gidx];
    const f32x4 g2 = *(const f32x4*)&gen[512 + gidx];
    f32x4 As;
    As.x = p0*g0.x + p1*g1.x + p2*g2.x;
    As.y = p0*g0.y + p1*g1.y + p2*g2.y;
    As.z = p0*g0.z + p1*g1.z + p2*g2.z;
    As.w = p0*g0.w + p1*g1.w + p2*g2.w;

    // Frobenius norm -> scaling exponent (wave-uniform)
    float t = As.x*As.x + As.y*As.y + As.z*As.z + As.w*As.w;
    #pragma unroll
    for (int m = 1; m <= 32; m <<= 1) t += __shfl_xor(t, m, 64);
    float theta = sqrtf(t);
    int s = 0;
    while (theta > 2.0f && s < 30) { theta *= 0.5f; ++s; }
    const float sc = exp2f((float)(-s));
    const f32x4 Xs = As * sc;

    // X into U0; cache X row
    write_strip(U0, r, c0, Xs);
    float xrow[16];
    read_row(U0, r, xrow);

    // A2 = X*X
    f32x4 a2s = {0.f, 0.f, 0.f, 0.f};
    mm_rowB(xrow, U0, c0, a2s);
    write_strip(U1, r, c0, a2s);

    // A3 = X*A2 (strip only; never needed as a matmul operand)
    f32x4 a3s = {0.f, 0.f, 0.f, 0.f};
    mm_rowB(xrow, U1, c0, a3s);

    // A4 = A2*A2
    float a2row[16];
    read_row(U1, r, a2row);
    f32x4 a4s = {0.f, 0.f, 0.f, 0.f};
    mm_rowB(a2row, U1, c0, a4s);
    write_strip(U0, r, c0, a4s);       // U0 (X) dead as matmul operand now
    float a4row[16];
    read_row(U0, r, a4row);

    // Degree-3 coefficient blocks (all register strips)
    f32x4 di = {0.f, 0.f, 0.f, 0.f};
    if (r >= c0 && r < c0 + 4) ((float*)&di)[r - c0] = 1.0f;

    const f32x4 C0 = di + Xs + a2s * 0.5f + a3s * (1.0f/6.0f);
    const f32x4 C1 = di * (1.0f/24.0f) + Xs * (1.0f/120.0f)
                   + a2s * (1.0f/720.0f) + a3s * (1.0f/5040.0f);
    const f32x4 Q2 = di * (1.0f/40320.0f) + Xs * (1.0f/362880.0f)
                   + a2s * (1.0f/3628800.0f) + a3s * (1.0f/39916800.0f)
                   + a4s * (1.0f/479001600.0f);

    // T1 = C1 + A4*Q2
    write_strip(U1, r, c0, Q2);
    f32x4 T1 = C1;
    mm_rowB(a4row, U1, c0, T1);

    // P = C0 + A4*T1
    write_strip(U1, r, c0, T1);
    f32x4 P = C0;
    mm_rowB(a4row, U1, c0, P);

    // s squarings (s wave-uniform; no barriers -> divergence-safe)
    for (int it = 0; it < s; ++it) {
        write_strip(U1, r, c0, P);
        float prow[16];
        read_row(U1, r, prow);
        f32x4 Pn = {0.f, 0.f, 0.f, 0.f};
        mm_rowB(prow, U1, c0, Pn);
        P = Pn;
    }

    // store Om row-major (element [r][c] at r*16+c), coalesced b128
    *(f32x4*)&Om[(size_t)bn * 256 + r * 16 + c0] = P;

    // v[c] = sum_r Om[r][c] * mu[r]; reduce over r (xor masks 4..32)
    const float mur = mu[bn * 16 + r];
    f32x4 vc = P * mur;
    #pragma unroll
    for (int m = 4; m <= 32; m <<= 1) {
        vc.x += __shfl_xor(vc.x, m, 64);
        vc.y += __shfl_xor(vc.y, m, 64);
        vc.z += __shfl_xor(vc.z, m, 64);
        vc.w += __shfl_xor(vc.w, m, 64);
    }
    if (r == 0) *(f32x4*)&v[bn * 16 + c0] = vc;

    float qp = vc.x*vc.x + vc.y*vc.y + vc.z*vc.z + vc.w*vc.w;
    qp += __shfl_xor(qp, 1, 64);
    qp += __shfl_xor(qp, 2, 64);
    if (lane == 0) q[bn] = 0.5f * qp;
}

// -------------------------------------------------------------------------
// Kernel 2: memory-bound pass over beta. One wave per (b,i); 4 i per block
// sharing a transposed LDS copy of v[b]. beta h-mean via f32x4 nontemporal
// loads (the HBM stream). Reductions: butterfly only sacc,R (12 shuffles);
// fold wc = (1-s)w1 + w2; halving-exchange over 16 comps (17 shuffles) so
// lane l ends with full wc[c], c=(l>>2)&15; rotation by Om_i distributed
// over all 64 lanes with a 5-shuffle c-group reduction. 34 DS-shuffles
// total vs 204 for the naive butterfly.
// -------------------------------------------------------------------------
__global__ __launch_bounds__(256, 4) void grad_kernel(
    const float* __restrict__ mu, const float* __restrict__ beta,
    const float* __restrict__ mu_prior, const float* __restrict__ lrp,
    const float* __restrict__ Om, const float* __restrict__ v,
    const float* __restrict__ q, float* __restrict__ out)
{
    __shared__ float v_t[16 * 516];      // 16 rows x 129 float4 (pad 1 f4)
    __shared__ f32x4 q4[128];

    const int blk = blockIdx.x;          // 0..1023
    const int b   = blk >> 7;
    const int i0  = (blk & 127) << 2;
    const int tid = threadIdx.x;
    const int wid = tid >> 6, lane = tid & 63;

    // stage v[b] transposed into LDS (dwordx4 global reads)
    const float* vb = v + (size_t)b * N_ * K_;
    for (int f4 = tid; f4 < (N_ * K_) / 4; f4 += 256) {
        const f32x4 tq = *(const f32x4*)&vb[f4 << 2];
        const int j  = f4 >> 2;
        const int k0 = (f4 & 3) << 2;
        v_t[(k0+0) * 516 + j] = tq.x;
        v_t[(k0+1) * 516 + j] = tq.y;
        v_t[(k0+2) * 516 + j] = tq.z;
        v_t[(k0+3) * 516 + j] = tq.w;
    }
    const f32x4* qb4 = (const f32x4*)(q + (size_t)b * N_);
    if (tid < 128) q4[tid] = qb4[tid];
    __syncthreads();

    const int i = i0 + wid;

    float vi[16];
    #pragma unroll
    for (int k = 0; k < 16; ++k) vi[k] = v_t[k * 516 + i];   // broadcast
    const float qi = ((const float*)q4)[i];

    float w1[16], w2[16];
    #pragma unroll
    for (int k = 0; k < 16; ++k) { w1[k] = 0.f; w2[k] = 0.f; }
    float sacc = 0.f, R = 0.f;

    const size_t betaBase = (((size_t)b * H_) * N_ + i) * N_;

    #pragma unroll 1
    for (int p = 0; p < 2; ++p) {
        const int j0 = (lane << 2) | (p << 8);

        const float* bp = beta + betaBase + j0;
        float rx = 0.f, ry = 0.f, rz = 0.f, rw = 0.f;
        #pragma unroll
        for (int h = 0; h < H_; ++h) {
            const f32x4 bt = __builtin_nontemporal_load(
                (const f32x4*)(bp + (size_t)h * NN_));
            rx += bt.x; ry += bt.y; rz += bt.z; rw += bt.w;
        }
        rx *= 0.125f; ry *= 0.125f; rz *= 0.125f; rw *= 0.125f;

        float d0 = 0.f, d1 = 0.f, d2 = 0.f, d3 = 0.f;
        #pragma unroll
        for (int k = 0; k < 16; ++k) {
            const f32x4 vj = *(const f32x4*)&v_t[k * 516 + j0];
            d0 = fmaf(vi[k], vj.x, d0);
            d1 = fmaf(vi[k], vj.y, d1);
            d2 = fmaf(vi[k], vj.z, d2);
            d3 = fmaf(vi[k], vj.w, d3);
        }
        const f32x4 qj = q4[lane | (p << 6)];
        const float rkl0 = rx * (qi + qj.x - d0);
        const float rkl1 = ry * (qi + qj.y - d1);
        const float rkl2 = rz * (qi + qj.z - d2);
        const float rkl3 = rw * (qi + qj.w - d3);
        sacc += (rkl0 + rkl1) + (rkl2 + rkl3);
        R    += (rx + ry) + (rz + rw);

        #pragma unroll
        for (int k = 0; k < 16; ++k) {
            const f32x4 vj = *(const f32x4*)&v_t[k * 516 + j0];
            float a1 = fmaf(rx, vj.x, w1[k]);
            a1 = fmaf(ry, vj.y, a1);
            a1 = fmaf(rz, vj.z, a1);
            w1[k] = fmaf(rw, vj.w, a1);
            float a2 = fmaf(rkl0, vj.x, w2[k]);
            a2 = fmaf(rkl1, vj.y, a2);
            a2 = fmaf(rkl2, vj.z, a2);
            w2[k] = fmaf(rkl3, vj.w, a2);
        }
    }

    // ---- stage A: full butterfly for the two scalars only ----
    #pragma unroll
    for (int off = 32; off > 0; off >>= 1) {
        sacc += __shfl_xor(sacc, off, 64);
        R    += __shfl_xor(R,    off, 64);
    }
    const float oms  = 1.0f - sacc;
    const float coef = oms * R + sacc;

    // ---- stage B: fold wc = (1-s)*w1 + w2 (oms is wave-uniform) ----
    float wc[16];
    #pragma unroll
    for (int k = 0; k < 16; ++k) wc[k] = fmaf(oms, w1[k], w2[k]);

    // ---- stage C: halving exchange; lane ends with sum of wc[c],
    //      c = (lane>>2)&15 ----
    {
        #pragma unroll
        for (int k = 0; k < 8; ++k) {             // mask 32, keep 8
            const bool up = (lane & 32) != 0;
            const float send = up ? wc[k] : wc[k + 8];
            const float recv = __shfl_xor(send, 32, 64);
            wc[k] = (up ? wc[k + 8] : wc[k]) + recv;
        }
        #pragma unroll
        for (int k = 0; k < 4; ++k) {             // mask 16, keep 4
            const bool up = (lane & 16) != 0;
            const float send = up ? wc[k] : wc[k + 4];
            const float recv = __shfl_xor(send, 16, 64);
            wc[k] = (up ? wc[k + 4] : wc[k]) + recv;
        }
        #pragma unroll
        for (int k = 0; k < 2; ++k) {             // mask 8, keep 2
            const bool up = (lane & 8) != 0;
            const float send = up ? wc[k] : wc[k + 2];
            const float recv = __shfl_xor(send, 8, 64);
            wc[k] = (up ? wc[k + 2] : wc[k]) + recv;
        }
        {                                          // mask 4, keep 1
            const bool up = (lane & 4) != 0;
            const float send = up ? wc[0] : wc[1];
            const float recv = __shfl_xor(send, 4, 64);
            wc[0] = (up ? wc[1] : wc[0]) + recv;
        }
        wc[0] += __shfl_xor(wc[0], 2, 64);
        wc[0] += __shfl_xor(wc[0], 1, 64);
    }

    // ---- stage D: distributed rotation. lane handles component c and
    //      4 rows 4t..4t+3 (t = lane&3) of Om_i; 5-shuffle c-reduction ----
    const int cmine = (lane >> 2) & 15;
    const float gv = coef * v_t[cmine * 516 + i] - wc[0];

    const size_t rowi = (size_t)b * N_ + i;
    const float* omb = Om + rowi * 256;
    const int tq = lane & 3;
    float pr[4];
    #pragma unroll
    for (int rr = 0; rr < 4; ++rr)
        pr[rr] = omb[(4 * tq + rr) * 16 + cmine] * gv;

    #pragma unroll
    for (int k = 0; k < 2; ++k) {                 // mask 4, keep 2
        const bool up = (lane & 4) != 0;
        const float send = up ? pr[k] : pr[k + 2];
        const float recv = __shfl_xor(send, 4, 64);
        pr[k] = (up ? pr[k + 2] : pr[k]) + recv;
    }
    {                                              // mask 8, keep 1
        const bool up = (lane & 8) != 0;
        const float send = up ? pr[0] : pr[1];
        const float recv = __shfl_xor(send, 8, 64);
        pr[0] = (up ? pr[1] : pr[0]) + recv;
    }
    pr[0] += __shfl_xor(pr[0], 16, 64);
    pr[0] += __shfl_xor(pr[0], 32, 64);
    // lane now holds S_row, row = 4t + 2*bit2 + bit3

    if (lane < 16) {
        const int row = 4 * tq + 2 * ((lane >> 2) & 1) + ((lane >> 3) & 1);
        const float lr = lrp[0];
        const size_t oi = rowi * 16 + row;
        const float m0 = mu[oi], mp = mu_prior[oi];
        out[oi] = m0 - lr * (ALPHA_C * (m0 - mp) + pr[0]);
    }
}

// -------------------------------------------------------------------------
extern "C" void kernel_launch(void* const* d_in, const int* in_sizes, int n_in,
                              void* d_out, int out_size, void* d_ws, size_t ws_size,
                              hipStream_t stream)
{
    const float* mu   = (const float*)d_in[0];
    const float* beta = (const float*)d_in[1];
    const float* mup  = (const float*)d_in[2];
    const float* phi  = (const float*)d_in[3];
    const float* gen  = (const float*)d_in[4];
    const float* lr   = (const float*)d_in[5];
    float* out = (float*)d_out;

    float* Om = (float*)d_ws;                       // 4096*256 floats = 4 MB
    float* v  = Om + (size_t)4096 * 256;            // 4096*16
    float* q  = v  + (size_t)4096 * 16;             // 4096

    expm_kernel<<<B_ * N_ / 4, 256, 0, stream>>>(mu, phi, gen, Om, v, q);
    grad_kernel<<<B_ * (N_ / 4), 256, 0, stream>>>(mu, beta, mup, lr, Om, v, q, out);
}